// Round 5
// baseline (2427.387 us; speedup 1.0000x reference)
//
#include <hip/hip_runtime.h>
#include <stdint.h>

// Elman RNN, B=64 T=512 E=H=O=512, fp32 in/out, bf16 MFMA compute.
// Pipeline: cast x -> bf16; transpose W1,W2 -> [N][K] bf16;
//   Phase A: Xc1 = x@W1x + b1            (parallel GEMM, bf16 out, into d_out scratch)
//   Phase B: h_{t+1}=sigmoid(Xc1[t]+h@W1h)  (64 WGs, 1 per batch, W1h in VGPRs)
//   Phase C: out = x@W2x + Hall@W2h + b2 (parallel GEMM K=1024, f32 out)
// R4 -> R5: elman_rec VGPR_Count=64 proved the compiler rematerialized the
// W1h fragment loads inside the t-loop (L2 reload of 512B/lane/step on the
// serial path -> 9900 cy/step). Fix: launder fragments through empty
// asm volatile ("+v") so they are opaque, non-rematerializable register
// values pinned for the whole loop.

typedef unsigned short u16;
typedef short s16;
typedef s16 s16x8 __attribute__((ext_vector_type(8)));
typedef u16 u16x8 __attribute__((ext_vector_type(8)));
typedef float f32x4 __attribute__((ext_vector_type(4)));

__device__ __forceinline__ u16 f2b(float f) {  // f32 -> bf16 RNE
  uint32_t x = __float_as_uint(f);
  uint32_t r = x + 0x7FFFu + ((x >> 16) & 1u);
  return (u16)(r >> 16);
}
__device__ __forceinline__ float b2f(u16 u) {
  return __uint_as_float(((uint32_t)u) << 16);
}

typedef const __attribute__((address_space(1))) uint32_t* gp32;
typedef __attribute__((address_space(3))) uint32_t* lp32;
__device__ __forceinline__ void gload_lds16(const void* g, void* l) {
  __builtin_amdgcn_global_load_lds((gp32)g, (lp32)l, 16, 0, 0);
}

// ---------------- cast x (f32 -> bf16), 8 elems/thread ----------------
__global__ __launch_bounds__(256) void cast_x_kernel(const float* __restrict__ x,
                                                     u16* __restrict__ xb, int n) {
  int i = (blockIdx.x * 256 + threadIdx.x) * 8;
  if (i >= n) return;
  const float4* p = (const float4*)(x + i);
  float4 v0 = p[0], v1 = p[1];
  u16x8 o;
  o[0] = f2b(v0.x); o[1] = f2b(v0.y); o[2] = f2b(v0.z); o[3] = f2b(v0.w);
  o[4] = f2b(v1.x); o[5] = f2b(v1.y); o[6] = f2b(v1.z); o[7] = f2b(v1.w);
  *(u16x8*)(xb + i) = o;
}

// -------- W [1024][512] f32 -> WT [512][1024] bf16 (LDS tiled) --------
__global__ __launch_bounds__(256) void transpose_cast_kernel(const float* __restrict__ W,
                                                             u16* __restrict__ WT) {
  __shared__ u16 tile[32][33];
  int tx = threadIdx.x, ty = threadIdx.y;
  int kt = blockIdx.x * 32, nt = blockIdx.y * 32;
#pragma unroll
  for (int i = 0; i < 4; ++i) {
    int k = kt + ty + i * 8;
    tile[ty + i * 8][tx] = f2b(W[k * 512 + nt + tx]);
  }
  __syncthreads();
#pragma unroll
  for (int i = 0; i < 4; ++i) {
    int n = nt + ty + i * 8;
    WT[n * 1024 + kt + tx] = tile[tx][ty + i * 8];
  }
}

// ---------------- GEMM: C[M=32768][512] = A@B^T + bias ----------------
// A rows: k<512 from A1 (ld 512), k>=512 from A2 (ld 512). BT: [512][1024].
// 128x128 tile, BK=64, 4 waves, each wave a 64x64 quadrant (4x4 16x16 frags).
__global__ __launch_bounds__(256) void gemm_kernel(
    const u16* __restrict__ A1, const u16* __restrict__ A2,
    const u16* __restrict__ BT, const float* __restrict__ bias,
    void* __restrict__ Cout, int K2, int outF32) {
  __shared__ u16 As[128 * 64];
  __shared__ u16 Bs[128 * 64];
  int tid = threadIdx.x;
  int lane = tid & 63, w = tid >> 6, wm = w >> 1, wn = w & 1;
  int cg = lane >> 4, cl = lane & 15;
  int m0 = blockIdx.x * 128, n0 = blockIdx.y * 128;
  int KT = (512 + K2) / 64;

  f32x4 z = {0.f, 0.f, 0.f, 0.f};
  f32x4 acc[4][4];
#pragma unroll
  for (int i = 0; i < 4; ++i)
#pragma unroll
    for (int j = 0; j < 4; ++j) acc[i][j] = z;

  int arow = tid >> 3;        // 0..31
  int kc = (tid & 7) * 8;     // 0..56

  for (int kt = 0; kt < KT; ++kt) {
    int kg = kt * 64;
    const u16* Abase;
    int kA;
    if (kg < 512) { Abase = A1; kA = kg; }
    else          { Abase = A2; kA = kg - 512; }
#pragma unroll
    for (int r = 0; r < 4; ++r) {
      const u16* ga = Abase + (size_t)(m0 + r * 32 + arow) * 512 + kA + kc;
      gload_lds16(ga, As + r * 2048 + tid * 8);
      const u16* gb = BT + (size_t)(n0 + r * 32 + arow) * 1024 + kg + kc;
      gload_lds16(gb, Bs + r * 2048 + tid * 8);
    }
    __syncthreads();   // drains vmcnt(0): staged tiles visible
#pragma unroll
    for (int ks = 0; ks < 2; ++ks) {
      s16x8 af[4], bf[4];
#pragma unroll
      for (int i = 0; i < 4; ++i)
        af[i] = *(const s16x8*)(As + (wm * 64 + i * 16 + cl) * 64 + ks * 32 + cg * 8);
#pragma unroll
      for (int j = 0; j < 4; ++j)
        bf[j] = *(const s16x8*)(Bs + (wn * 64 + j * 16 + cl) * 64 + ks * 32 + cg * 8);
#pragma unroll
      for (int i = 0; i < 4; ++i)
#pragma unroll
        for (int j = 0; j < 4; ++j)
          acc[i][j] = __builtin_amdgcn_mfma_f32_16x16x32_bf16(af[i], bf[j], acc[i][j], 0, 0, 0);
    }
    __syncthreads();
  }

  // epilogue: C/D mapping col=lane&15, row=(lane>>4)*4+reg
#pragma unroll
  for (int i = 0; i < 4; ++i) {
#pragma unroll
    for (int j = 0; j < 4; ++j) {
      int col = n0 + wn * 64 + j * 16 + cl;
      float bv = bias[col];
      int row0 = m0 + wm * 64 + i * 16 + cg * 4;
#pragma unroll
      for (int r = 0; r < 4; ++r) {
        float v = acc[i][j][r] + bv;
        size_t off = (size_t)(row0 + r) * 512 + col;
        if (outF32) ((float*)Cout)[off] = v;
        else        ((u16*)Cout)[off] = f2b(v);
      }
    }
  }
}

// ---------------- Phase B: recurrence, one WG (16 waves) per batch ----------------
// W1h held in registers: wave w owns output cols [32w,32w+32) as 2 col-tiles.
// A operand = h broadcast into all 16 MFMA rows (row-mapping agnostic).
__global__ __launch_bounds__(1024, 1) void elman_rec_kernel(
    const u16* __restrict__ W1T, const u16* __restrict__ Xc1b,
    u16* __restrict__ Hall, float* __restrict__ outHidden) {
  __shared__ u16 hbuf[2][512];
  int b = blockIdx.x;
  int tid = threadIdx.x;
  int lane = tid & 63, w = tid >> 6;   // w: 0..15
  int cg = lane >> 4, cl = lane & 15;

  // B fragments: lane -> W1h[k = kb*32 + cg*8 + j][n], n = 32w (+16) + cl
  s16x8 bfrag0[16], bfrag1[16];
  {
    const u16* base0 = W1T + (size_t)(w * 32 + cl) * 1024 + 512;
    const u16* base1 = W1T + (size_t)(w * 32 + 16 + cl) * 1024 + 512;
#pragma unroll
    for (int kb = 0; kb < 16; ++kb) {
      bfrag0[kb] = *(const s16x8*)(base0 + kb * 32 + cg * 8);
      bfrag1[kb] = *(const s16x8*)(base1 + kb * 32 + cg * 8);
    }
  }
  // Pin fragments in VGPRs: opaque to the compiler -> cannot be
  // rematerialized as in-loop L2 reloads (R4: VGPR_Count=64 pathology).
#pragma unroll
  for (int kb = 0; kb < 16; ++kb) {
    asm volatile("" : "+v"(bfrag0[kb]));
    asm volatile("" : "+v"(bfrag1[kb]));
  }

  if (tid < 512) {
    hbuf[0][tid] = 0;                                  // h_0 = 0
    Hall[(size_t)b * 512 * 512 + tid] = 0;             // Hall[b][0][:] = 0
  }
  __syncthreads();

  const u16* xcbase = Xc1b + (size_t)b * 512 * 512;
  int col0 = w * 32 + cl, col1 = w * 32 + 16 + cl;
  int cur = 0;
  for (int t = 0; t < 512; ++t) {
    const u16* xr = xcbase + t * 512;
    u16 xu0 = xr[col0], xu1 = xr[col1];                // prefetch early

    s16x8 a[16];
#pragma unroll
    for (int kb = 0; kb < 16; ++kb)
      a[kb] = *(const s16x8*)(&hbuf[cur][kb * 32 + cg * 8]);

    f32x4 a0a = {0.f,0.f,0.f,0.f}, a0b = a0a, a1a = a0a, a1b = a0a;  // 2-way K-split for ILP
#pragma unroll
    for (int kb = 0; kb < 8; ++kb) {
      a0a = __builtin_amdgcn_mfma_f32_16x16x32_bf16(a[kb], bfrag0[kb], a0a, 0, 0, 0);
      a1a = __builtin_amdgcn_mfma_f32_16x16x32_bf16(a[kb], bfrag1[kb], a1a, 0, 0, 0);
      a0b = __builtin_amdgcn_mfma_f32_16x16x32_bf16(a[kb + 8], bfrag0[kb + 8], a0b, 0, 0, 0);
      a1b = __builtin_amdgcn_mfma_f32_16x16x32_bf16(a[kb + 8], bfrag1[kb + 8], a1b, 0, 0, 0);
    }
    float pre0 = b2f(xu0) + a0a[0] + a0b[0];
    float pre1 = b2f(xu1) + a1a[0] + a1b[0];
    float h0 = 1.0f / (1.0f + __expf(-pre0));
    float h1 = 1.0f / (1.0f + __expf(-pre1));
    int nxt = cur ^ 1;
    if (lane < 16) {
      hbuf[nxt][col0] = f2b(h0);
      hbuf[nxt][col1] = f2b(h1);
      if (t < 511) {
        u16* hr = Hall + (size_t)b * 512 * 512 + (size_t)(t + 1) * 512;
        hr[col0] = f2b(h0);
        hr[col1] = f2b(h1);
      } else {
        outHidden[b * 512 + col0] = h0;
        outHidden[b * 512 + col1] = h1;
      }
    }
    __syncthreads();
    cur = nxt;
  }
}

extern "C" void kernel_launch(void* const* d_in, const int* in_sizes, int n_in,
                              void* d_out, int out_size, void* d_ws, size_t ws_size,
                              hipStream_t stream) {
  const float* x  = (const float*)d_in[0];
  const float* W1 = (const float*)d_in[1];
  const float* b1 = (const float*)d_in[2];
  const float* W2 = (const float*)d_in[3];
  const float* b2 = (const float*)d_in[4];
  float* out = (float*)d_out;

  char* ws = (char*)d_ws;
  u16* xb   = (u16*)(ws);                   // 33,554,432 B
  u16* W1T  = (u16*)(ws + 33554432);        //  1,048,576 B
  u16* W2T  = (u16*)(ws + 34603008);        //  1,048,576 B
  u16* Hall = (u16*)(ws + 35651584);        // 33,554,432 B  (total ~66 MB)
  u16* Xc1b = (u16*)d_out;                  // scratch in d_out bytes [0, 33.5MB)
                                            // (outHidden tail at byte 67.1MB untouched;
                                            //  phase C overwrites after Xc1b is dead)

  cast_x_kernel<<<8192, 256, 0, stream>>>(x, xb, 64 * 512 * 512);
  transpose_cast_kernel<<<dim3(32, 16), dim3(32, 8), 0, stream>>>(W1, W1T);
  transpose_cast_kernel<<<dim3(32, 16), dim3(32, 8), 0, stream>>>(W2, W2T);
  // Phase A: Xc1 = x @ W1x + b1  (bf16 out); A2 unused (K2=0)
  gemm_kernel<<<dim3(256, 4), 256, 0, stream>>>(xb, xb, W1T, b1, Xc1b, 0, 0);
  // Phase B: recurrence; writes Hall[b][1..511] and final hidden (f32) to out tail
  elman_rec_kernel<<<64, 1024, 0, stream>>>(W1T, Xc1b, Hall, out + 16777216);
  // Phase C: out = x @ W2x + Hall @ W2h + b2  (f32 out)
  gemm_kernel<<<dim3(256, 4), 256, 0, stream>>>(xb, Hall, W2T, b2, out, 512, 1);
}

// Round 8
// 1955.626 us; speedup vs baseline: 1.2412x; 1.2412x over previous
//
#include <hip/hip_runtime.h>
#include <stdint.h>

// Elman RNN, B=64 T=512 E=H=O=512, fp32 in/out, bf16 MFMA compute.
// Pipeline: cast x -> bf16; transpose W1,W2 -> [N][K] bf16;
//   Phase A: Xc1 = x@W1x + b1            (parallel GEMM, bf16 out, into d_out scratch)
//   Phase B: h_{t+1}=sigmoid(Xc1[t]+h@W1h)  (64 WGs x 8 waves; W1h STREAMED from L2)
//   Phase C: out = x@W2x + Hall@W2h + b2 (parallel GEMM K=1024, f32 out)
// R7 -> R8 redesign of phase B: W1h (512 KB) == entire CU register file
// (m69: pool 512 regs/SIMD), so register residency is impossible. Stream
// weights from L2 each step with an explicit 4-deep prefetch window (SSA
// renamed, static indices), 8 waves (halves the redundant LDS a-frag wall
// vs 16 waves), wave w owns 64 output cols as 4 N-tiles.

typedef unsigned short u16;
typedef short s16;
typedef s16 s16x8 __attribute__((ext_vector_type(8)));
typedef u16 u16x8 __attribute__((ext_vector_type(8)));
typedef float f32x4 __attribute__((ext_vector_type(4)));

__device__ __forceinline__ u16 f2b(float f) {  // f32 -> bf16 RNE
  uint32_t x = __float_as_uint(f);
  uint32_t r = x + 0x7FFFu + ((x >> 16) & 1u);
  return (u16)(r >> 16);
}
__device__ __forceinline__ float b2f(u16 u) {
  return __uint_as_float(((uint32_t)u) << 16);
}

typedef const __attribute__((address_space(1))) uint32_t* gp32;
typedef __attribute__((address_space(3))) uint32_t* lp32;
__device__ __forceinline__ void gload_lds16(const void* g, void* l) {
  __builtin_amdgcn_global_load_lds((gp32)g, (lp32)l, 16, 0, 0);
}

// ---------------- cast x (f32 -> bf16), 8 elems/thread ----------------
__global__ __launch_bounds__(256) void cast_x_kernel(const float* __restrict__ x,
                                                     u16* __restrict__ xb, int n) {
  int i = (blockIdx.x * 256 + threadIdx.x) * 8;
  if (i >= n) return;
  const float4* p = (const float4*)(x + i);
  float4 v0 = p[0], v1 = p[1];
  u16x8 o;
  o[0] = f2b(v0.x); o[1] = f2b(v0.y); o[2] = f2b(v0.z); o[3] = f2b(v0.w);
  o[4] = f2b(v1.x); o[5] = f2b(v1.y); o[6] = f2b(v1.z); o[7] = f2b(v1.w);
  *(u16x8*)(xb + i) = o;
}

// -------- W [1024][512] f32 -> WT [512][1024] bf16 (LDS tiled) --------
__global__ __launch_bounds__(256) void transpose_cast_kernel(const float* __restrict__ W,
                                                             u16* __restrict__ WT) {
  __shared__ u16 tile[32][33];
  int tx = threadIdx.x, ty = threadIdx.y;
  int kt = blockIdx.x * 32, nt = blockIdx.y * 32;
#pragma unroll
  for (int i = 0; i < 4; ++i) {
    int k = kt + ty + i * 8;
    tile[ty + i * 8][tx] = f2b(W[k * 512 + nt + tx]);
  }
  __syncthreads();
#pragma unroll
  for (int i = 0; i < 4; ++i) {
    int n = nt + ty + i * 8;
    WT[n * 1024 + kt + tx] = tile[tx][ty + i * 8];
  }
}

// ---------------- GEMM: C[M=32768][512] = A@B^T + bias ----------------
// A rows: k<512 from A1 (ld 512), k>=512 from A2 (ld 512). BT: [512][1024].
// 128x128 tile, BK=64, 4 waves, each wave a 64x64 quadrant (4x4 16x16 frags).
__global__ __launch_bounds__(256) void gemm_kernel(
    const u16* __restrict__ A1, const u16* __restrict__ A2,
    const u16* __restrict__ BT, const float* __restrict__ bias,
    void* __restrict__ Cout, int K2, int outF32) {
  __shared__ u16 As[128 * 64];
  __shared__ u16 Bs[128 * 64];
  int tid = threadIdx.x;
  int lane = tid & 63, w = tid >> 6, wm = w >> 1, wn = w & 1;
  int cg = lane >> 4, cl = lane & 15;
  int m0 = blockIdx.x * 128, n0 = blockIdx.y * 128;
  int KT = (512 + K2) / 64;

  f32x4 z = {0.f, 0.f, 0.f, 0.f};
  f32x4 acc[4][4];
#pragma unroll
  for (int i = 0; i < 4; ++i)
#pragma unroll
    for (int j = 0; j < 4; ++j) acc[i][j] = z;

  int arow = tid >> 3;        // 0..31
  int kc = (tid & 7) * 8;     // 0..56

  for (int kt = 0; kt < KT; ++kt) {
    int kg = kt * 64;
    const u16* Abase;
    int kA;
    if (kg < 512) { Abase = A1; kA = kg; }
    else          { Abase = A2; kA = kg - 512; }
#pragma unroll
    for (int r = 0; r < 4; ++r) {
      const u16* ga = Abase + (size_t)(m0 + r * 32 + arow) * 512 + kA + kc;
      gload_lds16(ga, As + r * 2048 + tid * 8);
      const u16* gb = BT + (size_t)(n0 + r * 32 + arow) * 1024 + kg + kc;
      gload_lds16(gb, Bs + r * 2048 + tid * 8);
    }
    __syncthreads();   // drains vmcnt(0): staged tiles visible
#pragma unroll
    for (int ks = 0; ks < 2; ++ks) {
      s16x8 af[4], bf[4];
#pragma unroll
      for (int i = 0; i < 4; ++i)
        af[i] = *(const s16x8*)(As + (wm * 64 + i * 16 + cl) * 64 + ks * 32 + cg * 8);
#pragma unroll
      for (int j = 0; j < 4; ++j)
        bf[j] = *(const s16x8*)(Bs + (wn * 64 + j * 16 + cl) * 64 + ks * 32 + cg * 8);
#pragma unroll
      for (int i = 0; i < 4; ++i)
#pragma unroll
        for (int j = 0; j < 4; ++j)
          acc[i][j] = __builtin_amdgcn_mfma_f32_16x16x32_bf16(af[i], bf[j], acc[i][j], 0, 0, 0);
    }
    __syncthreads();
  }

  // epilogue: C/D mapping col=lane&15, row=(lane>>4)*4+reg
#pragma unroll
  for (int i = 0; i < 4; ++i) {
#pragma unroll
    for (int j = 0; j < 4; ++j) {
      int col = n0 + wn * 64 + j * 16 + cl;
      float bv = bias[col];
      int row0 = m0 + wm * 64 + i * 16 + cg * 4;
#pragma unroll
      for (int r = 0; r < 4; ++r) {
        float v = acc[i][j][r] + bv;
        size_t off = (size_t)(row0 + r) * 512 + col;
        if (outF32) ((float*)Cout)[off] = v;
        else        ((u16*)Cout)[off] = f2b(v);
      }
    }
  }
}

// ---------------- Phase B: recurrence, one WG (8 waves) per batch ----------------
// Wave w owns output cols [64w, 64w+64) = 4 N-tiles. W1h streamed from L2
// every step via a 4-deep software-pipelined register window. A operand =
// h broadcast into all 16 MFMA rows (row 0 is the real batch row).
__global__ __launch_bounds__(512, 2) void elman_rec_kernel(
    const u16* __restrict__ W1T, const u16* __restrict__ Xc1b,
    u16* __restrict__ Hall, float* __restrict__ outHidden) {
  __shared__ u16 hbuf[2][512];
  int b = blockIdx.x;
  int tid = threadIdx.x;
  int lane = tid & 63, w = tid >> 6;   // w: 0..7
  int cg = lane >> 4, cl = lane & 15;

  // Weight base for this lane: W1h[k][n] at W1T[n*1024 + 512 + k],
  // n = 64w + 16nt + cl, k = 32kb + 8cg + j.
  const u16* wbase = W1T + (size_t)(w * 64 + cl) * 1024 + 512 + cg * 8;
  // frag(kb, nt) address = wbase + nt*16*1024 + kb*32

  if (tid < 512) {
    hbuf[0][tid] = 0;                                  // h_0 = 0
    Hall[(size_t)b * 512 * 512 + tid] = 0;             // Hall[b][0][:] = 0
  }
  __syncthreads();

  const u16* xcbase = Xc1b + (size_t)b * 512 * 512;
  int cur = 0;
  for (int t = 0; t < 512; ++t) {
    const u16* xr = xcbase + t * 512 + w * 64 + cl;
    u16 xu0 = xr[0], xu1 = xr[16], xu2 = xr[32], xu3 = xr[48];  // issue early

    s16x8 bq[4][4];   // weight window: slot kb&3, 4 N-tiles (SSA-renamed)
    s16x8 av[4];      // a-frag window: slot kb&3
#pragma unroll
    for (int kb = 0; kb < 4; ++kb) {
#pragma unroll
      for (int nt = 0; nt < 4; ++nt)
        bq[kb][nt] = *(const s16x8*)(wbase + nt * 16384 + kb * 32);
      av[kb] = *(const s16x8*)(&hbuf[cur][kb * 32 + cg * 8]);
    }

    f32x4 z = {0.f, 0.f, 0.f, 0.f};
    f32x4 acc0 = z, acc1 = z, acc2 = z, acc3 = z;
#pragma unroll
    for (int kb = 0; kb < 16; ++kb) {
      // copy current operands out of the window (free SSA copies)
      s16x8 a0 = av[kb & 3];
      s16x8 b0 = bq[kb & 3][0], b1 = bq[kb & 3][1];
      s16x8 b2 = bq[kb & 3][2], b3 = bq[kb & 3][3];
      // refill slot with kb+4 (keeps 4 K-tiles of loads in flight)
      if (kb < 12) {
#pragma unroll
        for (int nt = 0; nt < 4; ++nt)
          bq[kb & 3][nt] = *(const s16x8*)(wbase + nt * 16384 + (kb + 4) * 32);
        av[kb & 3] = *(const s16x8*)(&hbuf[cur][(kb + 4) * 32 + cg * 8]);
      }
      acc0 = __builtin_amdgcn_mfma_f32_16x16x32_bf16(a0, b0, acc0, 0, 0, 0);
      acc1 = __builtin_amdgcn_mfma_f32_16x16x32_bf16(a0, b1, acc1, 0, 0, 0);
      acc2 = __builtin_amdgcn_mfma_f32_16x16x32_bf16(a0, b2, acc2, 0, 0, 0);
      acc3 = __builtin_amdgcn_mfma_f32_16x16x32_bf16(a0, b3, acc3, 0, 0, 0);
    }

    // row 0 of C lives in reg 0 of the cg==0 group; cols = 64w + 16nt + cl
    float h0 = 1.0f / (1.0f + __expf(-(b2f(xu0) + acc0[0])));
    float h1 = 1.0f / (1.0f + __expf(-(b2f(xu1) + acc1[0])));
    float h2 = 1.0f / (1.0f + __expf(-(b2f(xu2) + acc2[0])));
    float h3 = 1.0f / (1.0f + __expf(-(b2f(xu3) + acc3[0])));
    int nxt = cur ^ 1;
    if (cg == 0) {
      int c = w * 64 + cl;
      hbuf[nxt][c]      = f2b(h0);
      hbuf[nxt][c + 16] = f2b(h1);
      hbuf[nxt][c + 32] = f2b(h2);
      hbuf[nxt][c + 48] = f2b(h3);
      if (t < 511) {
        u16* hr = Hall + (size_t)b * 512 * 512 + (size_t)(t + 1) * 512 + c;
        hr[0] = f2b(h0); hr[16] = f2b(h1); hr[32] = f2b(h2); hr[48] = f2b(h3);
      } else {
        float* ho = outHidden + b * 512 + c;
        ho[0] = h0; ho[16] = h1; ho[32] = h2; ho[48] = h3;
      }
    }
    __syncthreads();
    cur = nxt;
  }
}

extern "C" void kernel_launch(void* const* d_in, const int* in_sizes, int n_in,
                              void* d_out, int out_size, void* d_ws, size_t ws_size,
                              hipStream_t stream) {
  const float* x  = (const float*)d_in[0];
  const float* W1 = (const float*)d_in[1];
  const float* b1 = (const float*)d_in[2];
  const float* W2 = (const float*)d_in[3];
  const float* b2 = (const float*)d_in[4];
  float* out = (float*)d_out;

  char* ws = (char*)d_ws;
  u16* xb   = (u16*)(ws);                   // 33,554,432 B
  u16* W1T  = (u16*)(ws + 33554432);        //  1,048,576 B
  u16* W2T  = (u16*)(ws + 34603008);        //  1,048,576 B
  u16* Hall = (u16*)(ws + 35651584);        // 33,554,432 B  (total ~66 MB)
  u16* Xc1b = (u16*)d_out;                  // scratch in d_out bytes [0, 33.5MB)
                                            // (outHidden tail at byte 67.1MB untouched;
                                            //  phase C overwrites after Xc1b is dead)

  cast_x_kernel<<<8192, 256, 0, stream>>>(x, xb, 64 * 512 * 512);
  transpose_cast_kernel<<<dim3(32, 16), dim3(32, 8), 0, stream>>>(W1, W1T);
  transpose_cast_kernel<<<dim3(32, 16), dim3(32, 8), 0, stream>>>(W2, W2T);
  // Phase A: Xc1 = x @ W1x + b1  (bf16 out); A2 unused (K2=0)
  gemm_kernel<<<dim3(256, 4), 256, 0, stream>>>(xb, xb, W1T, b1, Xc1b, 0, 0);
  // Phase B: recurrence; writes Hall[b][1..511] and final hidden (f32) to out tail
  elman_rec_kernel<<<64, 512, 0, stream>>>(W1T, Xc1b, Hall, out + 16777216);
  // Phase C: out = x @ W2x + Hall @ W2h + b2  (f32 out)
  gemm_kernel<<<dim3(256, 4), 256, 0, stream>>>(xb, Hall, W2T, b2, out, 512, 1);
}

// Round 10
// 1319.936 us; speedup vs baseline: 1.8390x; 1.4816x over previous
//
#include <hip/hip_runtime.h>
#include <stdint.h>

// Elman RNN, B=64 T=512 E=H=O=512, fp32 in/out.
// R8 -> R9/R10: phase B was at the per-CU L2-BW roofline (512 KB bf16 W1h
// per CU-step = 8192 cy @64B/cy; measured 8250). Fix: W1h in fp8-e4m3 (x16
// scaled) = 256 KB -> 144 KB LDS-resident (preloaded once) + 112 KB/step
// streamed from L2 (~1750 cy; MFMA wall ~620 cy/SIMD). h quantized to e4m3
// only as MFMA A-operand; Hall stays bf16; phases A/C unchanged bf16.
// R10 fix: removed static attr_set guard (harness forbids static guards);
// hipFuncSetAttribute now called every launch (host-side, capture-safe).

typedef unsigned short u16;
typedef unsigned char u8;
typedef short s16;
typedef unsigned long long u64;
typedef s16 s16x8 __attribute__((ext_vector_type(8)));
typedef u16 u16x8 __attribute__((ext_vector_type(8)));
typedef float f32x4 __attribute__((ext_vector_type(4)));

__device__ __forceinline__ u16 f2b(float f) {  // f32 -> bf16 RNE
  uint32_t x = __float_as_uint(f);
  uint32_t r = x + 0x7FFFu + ((x >> 16) & 1u);
  return (u16)(r >> 16);
}
__device__ __forceinline__ float b2f(u16 u) {
  return __uint_as_float(((uint32_t)u) << 16);
}

// f32 -> OCP e4m3fn, RNE, saturate to 448. (bias 7, subnormals 2^-9 grid)
__device__ __forceinline__ u8 f2e4m3(float f) {
  uint32_t bits = __float_as_uint(f);
  uint32_t s = (bits >> 24) & 0x80u;
  uint32_t ax = bits & 0x7FFFFFFFu;
  float a = __uint_as_float(ax);
  if (a >= 448.f) return (u8)(s | 0x7Eu);
  int E = (int)(ax >> 23) - 127;
  if (E >= -6) {                       // normal e4m3
    uint32_t m23 = ax & 0x7FFFFFu;
    uint32_t r = m23 + 0x7FFFFu + ((m23 >> 20) & 1u);  // RNE to 3 bits
    uint32_t m;
    if (r >> 23) { E += 1; m = 0; } else { m = (r >> 20) & 7u; }
    if (E > 8) return (u8)(s | 0x7Eu);
    return (u8)(s | ((uint32_t)(E + 7) << 3) | m);
  }
  // subnormal: grid 2^-9
  int m = __float2int_rn(a * 512.0f);  // 0..8
  if (m <= 0) return (u8)s;
  if (m >= 8) return (u8)(s | 0x08u);
  return (u8)(s | (uint32_t)m);
}

typedef const __attribute__((address_space(1))) uint32_t* gp32;
typedef __attribute__((address_space(3))) uint32_t* lp32;
__device__ __forceinline__ void gload_lds16(const void* g, void* l) {
  __builtin_amdgcn_global_load_lds((gp32)g, (lp32)l, 16, 0, 0);
}

// ---------------- cast x (f32 -> bf16), 8 elems/thread ----------------
__global__ __launch_bounds__(256) void cast_x_kernel(const float* __restrict__ x,
                                                     u16* __restrict__ xb, int n) {
  int i = (blockIdx.x * 256 + threadIdx.x) * 8;
  if (i >= n) return;
  const float4* p = (const float4*)(x + i);
  float4 v0 = p[0], v1 = p[1];
  u16x8 o;
  o[0] = f2b(v0.x); o[1] = f2b(v0.y); o[2] = f2b(v0.z); o[3] = f2b(v0.w);
  o[4] = f2b(v1.x); o[5] = f2b(v1.y); o[6] = f2b(v1.z); o[7] = f2b(v1.w);
  *(u16x8*)(xb + i) = o;
}

// -------- W [1024][512] f32 -> WT [512][1024] bf16 (LDS tiled) --------
__global__ __launch_bounds__(256) void transpose_cast_kernel(const float* __restrict__ W,
                                                             u16* __restrict__ WT) {
  __shared__ u16 tile[32][33];
  int tx = threadIdx.x, ty = threadIdx.y;
  int kt = blockIdx.x * 32, nt = blockIdx.y * 32;
#pragma unroll
  for (int i = 0; i < 4; ++i) {
    int k = kt + ty + i * 8;
    tile[ty + i * 8][tx] = f2b(W[k * 512 + nt + tx]);
  }
  __syncthreads();
#pragma unroll
  for (int i = 0; i < 4; ++i) {
    int n = nt + ty + i * 8;
    WT[n * 1024 + kt + tx] = tile[tx][ty + i * 8];
  }
}

// ---- pack W1h (rows 512..1023 of W1) -> fp8 fragment-ordered buffers ----
// Fragment (w,nt,kb): 64 lanes x 8B. Lane (cg,cl) holds W1h[k=kb*32+cg*8+j]
// [n=w*64+nt*16+cl], j=0..7, value = e4m3(16*W). kb<9 -> res (LDS-resident,
// laid out [w][nt][kb]); kb>=9 -> str (streamed, [w][nt][kb-9]).
__global__ __launch_bounds__(256) void pack_w1h8_kernel(const float* __restrict__ W1,
                                                        u8* __restrict__ res,
                                                        u8* __restrict__ str) {
  int i = blockIdx.x * 256 + threadIdx.x;     // 32768 threads
  int lane = i & 63, kb = (i >> 6) & 15, nt = (i >> 10) & 3, w = i >> 12;
  int cl = lane & 15, cg = lane >> 4;
  int n = w * 64 + nt * 16 + cl;
  u64 pack = 0;
#pragma unroll
  for (int j = 0; j < 8; ++j) {
    int k = kb * 32 + cg * 8 + j;
    u8 v = f2e4m3(16.0f * W1[(size_t)(512 + k) * 512 + n]);
    pack |= ((u64)v) << (8 * j);
  }
  if (kb < 9) ((u64*)res)[(size_t)((w * 4 + nt) * 9 + kb) * 64 + lane] = pack;
  else        ((u64*)str)[(size_t)((w * 4 + nt) * 7 + (kb - 9)) * 64 + lane] = pack;
}

// ---------------- GEMM: C[M=32768][512] = A@B^T + bias ----------------
__global__ __launch_bounds__(256) void gemm_kernel(
    const u16* __restrict__ A1, const u16* __restrict__ A2,
    const u16* __restrict__ BT, const float* __restrict__ bias,
    void* __restrict__ Cout, int K2, int outF32) {
  __shared__ u16 As[128 * 64];
  __shared__ u16 Bs[128 * 64];
  int tid = threadIdx.x;
  int lane = tid & 63, w = tid >> 6, wm = w >> 1, wn = w & 1;
  int cg = lane >> 4, cl = lane & 15;
  int m0 = blockIdx.x * 128, n0 = blockIdx.y * 128;
  int KT = (512 + K2) / 64;

  f32x4 z = {0.f, 0.f, 0.f, 0.f};
  f32x4 acc[4][4];
#pragma unroll
  for (int i = 0; i < 4; ++i)
#pragma unroll
    for (int j = 0; j < 4; ++j) acc[i][j] = z;

  int arow = tid >> 3;
  int kc = (tid & 7) * 8;

  for (int kt = 0; kt < KT; ++kt) {
    int kg = kt * 64;
    const u16* Abase;
    int kA;
    if (kg < 512) { Abase = A1; kA = kg; }
    else          { Abase = A2; kA = kg - 512; }
#pragma unroll
    for (int r = 0; r < 4; ++r) {
      const u16* ga = Abase + (size_t)(m0 + r * 32 + arow) * 512 + kA + kc;
      gload_lds16(ga, As + r * 2048 + tid * 8);
      const u16* gb = BT + (size_t)(n0 + r * 32 + arow) * 1024 + kg + kc;
      gload_lds16(gb, Bs + r * 2048 + tid * 8);
    }
    __syncthreads();
#pragma unroll
    for (int ks = 0; ks < 2; ++ks) {
      s16x8 af[4], bf[4];
#pragma unroll
      for (int i = 0; i < 4; ++i)
        af[i] = *(const s16x8*)(As + (wm * 64 + i * 16 + cl) * 64 + ks * 32 + cg * 8);
#pragma unroll
      for (int j = 0; j < 4; ++j)
        bf[j] = *(const s16x8*)(Bs + (wn * 64 + j * 16 + cl) * 64 + ks * 32 + cg * 8);
#pragma unroll
      for (int i = 0; i < 4; ++i)
#pragma unroll
        for (int j = 0; j < 4; ++j)
          acc[i][j] = __builtin_amdgcn_mfma_f32_16x16x32_bf16(af[i], bf[j], acc[i][j], 0, 0, 0);
    }
    __syncthreads();
  }

#pragma unroll
  for (int i = 0; i < 4; ++i) {
#pragma unroll
    for (int j = 0; j < 4; ++j) {
      int col = n0 + wn * 64 + j * 16 + cl;
      float bv = bias[col];
      int row0 = m0 + wm * 64 + i * 16 + cg * 4;
#pragma unroll
      for (int r = 0; r < 4; ++r) {
        float v = acc[i][j][r] + bv;
        size_t off = (size_t)(row0 + r) * 512 + col;
        if (outF32) ((float*)Cout)[off] = v;
        else        ((u16*)Cout)[off] = f2b(v);
      }
    }
  }
}

// ------------- Phase B: fp8 recurrence, one WG (8 waves) per batch -------------
// LDS: 144 KB resident W1h8 (kb 0..8) + h8[2][512]. kb 9..15 streamed from
// L2 in-step (28 u64/wave, R8-proven register pattern). Wave w owns cols
// [64w,64w+64) as 4 N-tiles; A = h8 broadcast into all 16 rows.
__device__ __forceinline__ void elman_step(
    int t, int b, int w, int cg, int cl, int lane,
    const u8* __restrict__ lbase, const u8* __restrict__ gbase,
    const u8* __restrict__ h8r, u8* __restrict__ h8w,
    const u16* __restrict__ xcbase, u16* __restrict__ Hall,
    float* __restrict__ outHidden) {
  // streamed weights (kb 9..15), issued first so latency hides under LDS part
  u64 ws[4][7];
#pragma unroll
  for (int nt = 0; nt < 4; ++nt)
#pragma unroll
    for (int kbs = 0; kbs < 7; ++kbs)
      ws[nt][kbs] = *(const u64*)(gbase + (size_t)(nt * 7 + kbs) * 512);

  const u16* xr = xcbase + (size_t)t * 512 + w * 64 + cl;
  u16 xu0 = xr[0], xu1 = xr[16], xu2 = xr[32], xu3 = xr[48];

  u64 ah[16];
#pragma unroll
  for (int kb = 0; kb < 16; ++kb)
    ah[kb] = *(const u64*)(h8r + kb * 32 + cg * 8);

  f32x4 z = {0.f, 0.f, 0.f, 0.f};
  f32x4 acc0 = z, acc1 = z, acc2 = z, acc3 = z;
#pragma unroll
  for (int kb = 0; kb < 9; ++kb) {  // LDS-resident part
    u64 b0 = *(const u64*)(lbase + (0 * 9 + kb) * 512);
    u64 b1 = *(const u64*)(lbase + (1 * 9 + kb) * 512);
    u64 b2 = *(const u64*)(lbase + (2 * 9 + kb) * 512);
    u64 b3 = *(const u64*)(lbase + (3 * 9 + kb) * 512);
    acc0 = __builtin_amdgcn_mfma_f32_16x16x32_fp8_fp8((long long)ah[kb], (long long)b0, acc0, 0, 0, 0);
    acc1 = __builtin_amdgcn_mfma_f32_16x16x32_fp8_fp8((long long)ah[kb], (long long)b1, acc1, 0, 0, 0);
    acc2 = __builtin_amdgcn_mfma_f32_16x16x32_fp8_fp8((long long)ah[kb], (long long)b2, acc2, 0, 0, 0);
    acc3 = __builtin_amdgcn_mfma_f32_16x16x32_fp8_fp8((long long)ah[kb], (long long)b3, acc3, 0, 0, 0);
  }
#pragma unroll
  for (int kbs = 0; kbs < 7; ++kbs) {  // streamed part
    acc0 = __builtin_amdgcn_mfma_f32_16x16x32_fp8_fp8((long long)ah[9 + kbs], (long long)ws[0][kbs], acc0, 0, 0, 0);
    acc1 = __builtin_amdgcn_mfma_f32_16x16x32_fp8_fp8((long long)ah[9 + kbs], (long long)ws[1][kbs], acc1, 0, 0, 0);
    acc2 = __builtin_amdgcn_mfma_f32_16x16x32_fp8_fp8((long long)ah[9 + kbs], (long long)ws[2][kbs], acc2, 0, 0, 0);
    acc3 = __builtin_amdgcn_mfma_f32_16x16x32_fp8_fp8((long long)ah[9 + kbs], (long long)ws[3][kbs], acc3, 0, 0, 0);
  }

  const float inv16 = 0.0625f;
  float h0 = 1.0f / (1.0f + __expf(-(b2f(xu0) + acc0[0] * inv16)));
  float h1 = 1.0f / (1.0f + __expf(-(b2f(xu1) + acc1[0] * inv16)));
  float h2 = 1.0f / (1.0f + __expf(-(b2f(xu2) + acc2[0] * inv16)));
  float h3 = 1.0f / (1.0f + __expf(-(b2f(xu3) + acc3[0] * inv16)));
  if (cg == 0) {
    int c = w * 64 + cl;
    h8w[c]      = f2e4m3(h0);
    h8w[c + 16] = f2e4m3(h1);
    h8w[c + 32] = f2e4m3(h2);
    h8w[c + 48] = f2e4m3(h3);
    if (t < 511) {
      u16* hr = Hall + (size_t)b * 262144 + (size_t)(t + 1) * 512 + c;
      hr[0] = f2b(h0); hr[16] = f2b(h1); hr[32] = f2b(h2); hr[48] = f2b(h3);
    } else {
      float* ho = outHidden + b * 512 + c;
      ho[0] = h0; ho[16] = h1; ho[32] = h2; ho[48] = h3;
    }
  }
  __syncthreads();
}

__global__ __launch_bounds__(512, 2) void elman_rec_fp8_kernel(
    const u8* __restrict__ w8res, const u8* __restrict__ w8str,
    const u16* __restrict__ Xc1b, u16* __restrict__ Hall,
    float* __restrict__ outHidden) {
  extern __shared__ u8 sm[];
  u8* wlds = sm;                 // 147456 B resident weights
  u8* h8   = sm + 147456;        // 2 x 512 B hidden (fp8)
  int b = blockIdx.x;
  int tid = threadIdx.x;
  int lane = tid & 63, w = tid >> 6;   // w: 0..7
  int cg = lane >> 4, cl = lane & 15;

  // stage resident weights: 147456 B = 18 iters x (512 thr x 16 B)
  for (int it = 0; it < 18; ++it)
    gload_lds16(w8res + it * 8192 + tid * 16, wlds + it * 8192 + tid * 16);
  if (tid < 512) {
    h8[tid] = 0; h8[512 + tid] = 0;
    Hall[(size_t)b * 262144 + tid] = 0;
  }
  __syncthreads();  // drains vmcnt(0) -> staged weights visible

  const u8* lbase = wlds + (size_t)w * (4 * 9 * 512) + lane * 8;
  const u8* gbase = w8str + (size_t)w * (4 * 7 * 512) + lane * 8;
  const u16* xcbase = Xc1b + (size_t)b * 262144;

  for (int tt = 0; tt < 512; tt += 2) {
    elman_step(tt,     b, w, cg, cl, lane, lbase, gbase, h8,       h8 + 512, xcbase, Hall, outHidden);
    elman_step(tt + 1, b, w, cg, cl, lane, lbase, gbase, h8 + 512, h8,       xcbase, Hall, outHidden);
  }
}

extern "C" void kernel_launch(void* const* d_in, const int* in_sizes, int n_in,
                              void* d_out, int out_size, void* d_ws, size_t ws_size,
                              hipStream_t stream) {
  const float* x  = (const float*)d_in[0];
  const float* W1 = (const float*)d_in[1];
  const float* b1 = (const float*)d_in[2];
  const float* W2 = (const float*)d_in[3];
  const float* b2 = (const float*)d_in[4];
  float* out = (float*)d_out;

  char* ws = (char*)d_ws;
  u16* xb      = (u16*)(ws);                 // 33,554,432 B
  u16* W1T     = (u16*)(ws + 33554432);      //  1,048,576 B
  u16* W2T     = (u16*)(ws + 34603008);      //  1,048,576 B
  u16* Hall    = (u16*)(ws + 35651584);      // 33,554,432 B
  u8*  W1h8res = (u8*)(ws + 69206016);       //    147,456 B
  u8*  W1h8str = (u8*)(ws + 69353472);       //    114,688 B  (total ~66.3 MB)
  u16* Xc1b    = (u16*)d_out;                // scratch in d_out [0, 33.5MB)

  // Opt-in to >64KB dynamic LDS. Called EVERY launch (no static guards —
  // harness rule); host-side attribute setter, safe under graph capture.
  hipFuncSetAttribute((const void*)elman_rec_fp8_kernel,
                      hipFuncAttributeMaxDynamicSharedMemorySize, 148480);

  cast_x_kernel<<<8192, 256, 0, stream>>>(x, xb, 64 * 512 * 512);
  transpose_cast_kernel<<<dim3(32, 16), dim3(32, 8), 0, stream>>>(W1, W1T);
  transpose_cast_kernel<<<dim3(32, 16), dim3(32, 8), 0, stream>>>(W2, W2T);
  pack_w1h8_kernel<<<128, 256, 0, stream>>>(W1, W1h8res, W1h8str);
  // Phase A: Xc1 = x @ W1x + b1  (bf16 out)
  gemm_kernel<<<dim3(256, 4), 256, 0, stream>>>(xb, xb, W1T, b1, Xc1b, 0, 0);
  // Phase B: fp8 recurrence
  elman_rec_fp8_kernel<<<64, 512, 148480, stream>>>(W1h8res, W1h8str, Xc1b, Hall, out + 16777216);
  // Phase C: out = x @ W2x + Hall @ W2h + b2  (f32 out)
  gemm_kernel<<<dim3(256, 4), 256, 0, stream>>>(xb, Hall, W2T, b2, out, 512, 1);
}